// Round 1
// baseline (902.075 us; speedup 1.0000x reference)
//
#include <hip/hip_runtime.h>
#include <stdint.h>

#define D_MODEL   1024
#define N_EXPERTS 8
#define D_HIDDEN  4096
#define T_TOKENS  8192
#define N_SLOTS   (T_TOKENS * 2)
#define MAX_TILES 136   // sum_e ceil(n_e/128) <= 16384/128 + 7 = 135

typedef __bf16 bf16x8 __attribute__((ext_vector_type(8)));
typedef float  f32x4  __attribute__((ext_vector_type(4)));
typedef unsigned short ushort8 __attribute__((ext_vector_type(8)));

__device__ __forceinline__ unsigned short f2bf(float f) {
    unsigned int u = __float_as_uint(f);
    u += 0x7fffu + ((u >> 16) & 1u);   // round-to-nearest-even
    return (unsigned short)(u >> 16);
}
__device__ __forceinline__ float bf2f(unsigned short v) {
    return __uint_as_float((unsigned int)v << 16);
}

__device__ __forceinline__ void gl_lds16(const void* g, void* l) {
    __builtin_amdgcn_global_load_lds(
        (const __attribute__((address_space(1))) unsigned int*)g,
        (__attribute__((address_space(3))) unsigned int*)l, 16, 0, 0);
}

// ------- gating: logits -> top2 -> softmax -> counts; also converts x->bf16 -------
// 512 blocks x 256 thr; 16 tokens/block (4 waves x 4 tokens)
__global__ __launch_bounds__(256) void gate_kernel(
    const float* __restrict__ x, const float* __restrict__ gw,
    unsigned short* __restrict__ xb,
    int* __restrict__ route_pack, float* __restrict__ route_w,
    int* __restrict__ cnt)
{
    __shared__ float gws[N_EXPERTS * D_MODEL];
    __shared__ int hist[N_EXPERTS];
    int tid = threadIdx.x;
    for (int i = tid * 4; i < N_EXPERTS * D_MODEL; i += 256 * 4)
        *(float4*)&gws[i] = *(const float4*)&gw[i];
    if (tid < N_EXPERTS) hist[tid] = 0;
    __syncthreads();

    int wave = tid >> 6, lane = tid & 63;
    for (int tt = 0; tt < 4; tt++) {
        int t = blockIdx.x * 16 + wave * 4 + tt;
        const float* xr = x + (size_t)t * D_MODEL;

        float acc[N_EXPERTS];
        for (int e = 0; e < N_EXPERTS; e++) acc[e] = 0.f;
        for (int i = 0; i < 4; i++) {
            float4 xv = *(const float4*)&xr[lane * 4 + i * 256];
            ushort4 o;
            o.x = f2bf(xv.x); o.y = f2bf(xv.y); o.z = f2bf(xv.z); o.w = f2bf(xv.w);
            *(ushort4*)&xb[(size_t)t * D_MODEL + lane * 4 + i * 256] = o;
            for (int e = 0; e < N_EXPERTS; e++) {
                float4 gv = *(const float4*)&gws[e * D_MODEL + lane * 4 + i * 256];
                acc[e] += xv.x * gv.x + xv.y * gv.y + xv.z * gv.z + xv.w * gv.w;
            }
        }
        for (int e = 0; e < N_EXPERTS; e++)
            for (int off = 32; off >= 1; off >>= 1)
                acc[e] += __shfl_xor(acc[e], off, 64);

        if (lane == 0) {
            int e0 = 0; float v0 = acc[0];
            for (int e = 1; e < N_EXPERTS; e++) if (acc[e] > v0) { v0 = acc[e]; e0 = e; }
            int e1 = (e0 == 0) ? 1 : 0; float v1 = acc[e1];
            for (int e = 0; e < N_EXPERTS; e++)
                if (e != e0 && acc[e] > v1) { v1 = acc[e]; e1 = e; }
            float w0 = 1.f / (1.f + __expf(v1 - v0));
            route_pack[t] = e0 | (e1 << 8);
            route_w[2 * t]     = w0;
            route_w[2 * t + 1] = 1.f - w0;
            atomicAdd(&hist[e0], 1);
            atomicAdd(&hist[e1], 1);
        }
    }
    __syncthreads();
    if (tid < N_EXPERTS) atomicAdd(&cnt[tid], hist[tid]);
}

__global__ void offsets_kernel(const int* __restrict__ cnt,
                               int* __restrict__ off, int* __restrict__ cnt2)
{
    if (threadIdx.x == 0) {
        int a = 0;
        for (int e = 0; e < N_EXPERTS; e++) { off[e] = a; a += cnt[e]; cnt2[e] = 0; }
        off[N_EXPERTS] = a;
    }
}

// ------- scatter via wave ballot-ranking: 1 wave = 64 tokens, 8 atomics/wave -------
__global__ __launch_bounds__(64) void scatter_kernel(
    const int* __restrict__ route_pack, const int* __restrict__ off,
    int* __restrict__ cnt2, int* __restrict__ tok_id, int* __restrict__ inv)
{
    int lane = threadIdx.x;
    int t = blockIdx.x * 64 + lane;
    int p  = route_pack[t];
    int e0 = p & 0xff, e1 = (p >> 8) & 0xff;

    unsigned long long m0[N_EXPERTS], m1[N_EXPERTS];
    for (int e = 0; e < N_EXPERTS; e++) {
        m0[e] = __ballot(e0 == e);
        m1[e] = __ballot(e1 == e);
    }
    int mybase = 0;
    if (lane < N_EXPERTS)
        mybase = atomicAdd(&cnt2[lane], __popcll(m0[lane]) + __popcll(m1[lane]));

    unsigned long long lt = (1ull << lane) - 1ull;
    int b0 = __shfl(mybase, e0);
    int s0 = off[e0] + b0 + (int)__popcll(m0[e0] & lt);
    int b1 = __shfl(mybase, e1);
    int s1 = off[e1] + b1 + (int)__popcll(m0[e1]) + (int)__popcll(m1[e1] & lt);

    tok_id[s0] = t;
    tok_id[s1] = t;
    inv[2 * t]     = s0;
    inv[2 * t + 1] = s1;
}

// src: [E][R][C] fp32  ->  dst: [E][C][R] bf16   (64x64 tiles, 16B-coalesced)
template <int R, int C>
__global__ __launch_bounds__(256) void transpose_convert_kernel(
    const float* __restrict__ src, unsigned short* __restrict__ dst)
{
    __shared__ float tile[64 * 68];
    int e = blockIdx.z;
    const float* s = src + (size_t)e * R * C;
    unsigned short* d = dst + (size_t)e * R * C;
    int r0 = blockIdx.y * 64, c0 = blockIdx.x * 64;
    int t = threadIdx.x;
    {
        int r = t >> 4, c4 = (t & 15) * 4;
        for (int p = 0; p < 4; p++, r += 16)
            *(float4*)&tile[r * 68 + c4] = *(const float4*)&s[(size_t)(r0 + r) * C + c0 + c4];
    }
    __syncthreads();
    {
        int c = t >> 2, rblk = (t & 3) * 8;
        for (int q = 0; q < 2; q++) {
            int rr = q * 32 + rblk;
            ushort8 o;
            for (int j = 0; j < 8; j++) o[j] = f2bf(tile[(rr + j) * 68 + c]);
            *(ushort8*)&d[(size_t)(c0 + c) * R + r0 + rr] = o;
        }
    }
}

// ---------------- grouped GEMM1: h = relu(x[tok] @ w1 + b1) ----------------
// m97-exact structure: 128x128 tile, BK=64, global_load_lds width 16, 2 barriers/K-step
__global__ __launch_bounds__(256) void gemm1_kernel(
    const unsigned short* __restrict__ xb, const unsigned short* __restrict__ w1t,
    const float* __restrict__ b1, const int* __restrict__ tok_id,
    const int* __restrict__ off, unsigned short* __restrict__ h)
{
    __shared__ unsigned short smem[2 * 128 * 64];   // As(16K)+Bs(16K); stage(17K) aliases
    unsigned short* As = smem;
    unsigned short* Bs = smem + 128 * 64;
    unsigned short* stage = smem;

    int bx = blockIdx.x;
    int e = -1, slot0 = 0, end = 0;
    {
        int acc = 0;
        for (int i = 0; i < N_EXPERTS; i++) {
            int s = off[i], en = off[i + 1];
            int nt = (en - s + 127) >> 7;
            if (e < 0 && bx < acc + nt) { e = i; slot0 = s + (bx - acc) * 128; end = en; }
            acc += nt;
        }
        if (e < 0) return;
    }
    int n0 = blockIdx.y * 128;
    int tid = threadIdx.x, wave = tid >> 6, lane = tid & 63;
    int lr = lane >> 3, lc = lane & 7;   // 8 rows x 8 col-chunks per wave per stage call

    f32x4 acc[4][4];
    const f32x4 zero = {0.f, 0.f, 0.f, 0.f};
    for (int i = 0; i < 4; i++) for (int j = 0; j < 4; j++) acc[i][j] = zero;

    // staging pointers: wave w, call c covers tile rows [w*32+c*8, +8)
    const unsigned short* gA[4];
    const unsigned short* gB[4];
    unsigned short* lA[4];
    unsigned short* lB[4];
#pragma unroll
    for (int c = 0; c < 4; c++) {
        int arow = wave * 32 + c * 8 + lr;
        int slot = min(slot0 + arow, end - 1);
        gA[c] = xb + (size_t)tok_id[slot] * D_MODEL + lc * 8;
        gB[c] = w1t + ((size_t)e * D_HIDDEN + n0 + arow) * D_MODEL + lc * 8;
        lA[c] = &As[(wave * 32 + c * 8) * 64];
        lB[c] = &Bs[(wave * 32 + c * 8) * 64];
    }

    int wm = wave & 1, wn = wave >> 1;
    int row16 = lane & 15, q8 = (lane >> 4) * 8;
    for (int k0 = 0; k0 < D_MODEL; k0 += 64) {
#pragma unroll
        for (int c = 0; c < 4; c++) {
            gl_lds16(gA[c] + k0, lA[c]);
            gl_lds16(gB[c] + k0, lB[c]);
        }
        __syncthreads();
#pragma unroll
        for (int ks = 0; ks < 2; ks++) {
            bf16x8 af[4], bfr[4];
#pragma unroll
            for (int i = 0; i < 4; i++)
                af[i] = *(const bf16x8*)&As[(wm * 64 + i * 16 + row16) * 64 + ks * 32 + q8];
#pragma unroll
            for (int j = 0; j < 4; j++)
                bfr[j] = *(const bf16x8*)&Bs[(wn * 64 + j * 16 + row16) * 64 + ks * 32 + q8];
#pragma unroll
            for (int i = 0; i < 4; i++)
#pragma unroll
                for (int j = 0; j < 4; j++)
                    acc[i][j] = __builtin_amdgcn_mfma_f32_16x16x32_bf16(af[i], bfr[j], acc[i][j], 0, 0, 0);
        }
        __syncthreads();
    }

    // epilogue: bias+relu -> bf16 stage in LDS (64x128, stride 136) -> 16B stores
    int quad = lane >> 4, col16 = lane & 15;
    for (int p = 0; p < 2; p++) {
        __syncthreads();
        if (wm == p) {
            for (int j = 0; j < 4; j++) {
                int n = n0 + wn * 64 + j * 16 + col16;
                float bias = b1[e * D_HIDDEN + n];
                for (int i = 0; i < 4; i++)
                    for (int r = 0; r < 4; r++) {
                        float v = acc[i][j][r] + bias;
                        v = v > 0.f ? v : 0.f;
                        stage[(i * 16 + quad * 4 + r) * 136 + wn * 64 + j * 16 + col16] = f2bf(v);
                    }
            }
        }
        __syncthreads();
        int row = tid >> 4, coff = (tid & 15) * 8;
        for (int rr = row; rr < 64; rr += 16) {
            int slot = slot0 + p * 64 + rr;
            if (slot < end)
                *(ushort8*)&h[(size_t)slot * D_HIDDEN + n0 + coff] =
                    *(const ushort8*)&stage[rr * 136 + coff];
        }
    }
}

// -------- grouped GEMM2: y[slot] = h[slot] @ w2 + b2  (bf16, store-only) --------
__global__ __launch_bounds__(256) void gemm2_kernel(
    const unsigned short* __restrict__ h, const unsigned short* __restrict__ w2t,
    const float* __restrict__ b2, const int* __restrict__ off,
    unsigned short* __restrict__ y)
{
    __shared__ unsigned short smem[2 * 128 * 64];
    unsigned short* As = smem;
    unsigned short* Bs = smem + 128 * 64;
    unsigned short* stage = smem;

    int bx = blockIdx.x;
    int e = -1, slot0 = 0, end = 0;
    {
        int acc = 0;
        for (int i = 0; i < N_EXPERTS; i++) {
            int s = off[i], en = off[i + 1];
            int nt = (en - s + 127) >> 7;
            if (e < 0 && bx < acc + nt) { e = i; slot0 = s + (bx - acc) * 128; end = en; }
            acc += nt;
        }
        if (e < 0) return;
    }
    int n0 = blockIdx.y * 128;
    int tid = threadIdx.x, wave = tid >> 6, lane = tid & 63;
    int lr = lane >> 3, lc = lane & 7;

    f32x4 acc[4][4];
    const f32x4 zero = {0.f, 0.f, 0.f, 0.f};
    for (int i = 0; i < 4; i++) for (int j = 0; j < 4; j++) acc[i][j] = zero;

    const unsigned short* gA[4];
    const unsigned short* gB[4];
    unsigned short* lA[4];
    unsigned short* lB[4];
#pragma unroll
    for (int c = 0; c < 4; c++) {
        int arow = wave * 32 + c * 8 + lr;
        int slot = min(slot0 + arow, end - 1);
        gA[c] = h + (size_t)slot * D_HIDDEN + lc * 8;
        gB[c] = w2t + ((size_t)e * D_MODEL + n0 + arow) * D_HIDDEN + lc * 8;
        lA[c] = &As[(wave * 32 + c * 8) * 64];
        lB[c] = &Bs[(wave * 32 + c * 8) * 64];
    }

    int wm = wave & 1, wn = wave >> 1;
    int row16 = lane & 15, q8 = (lane >> 4) * 8;
    for (int k0 = 0; k0 < D_HIDDEN; k0 += 64) {
#pragma unroll
        for (int c = 0; c < 4; c++) {
            gl_lds16(gA[c] + k0, lA[c]);
            gl_lds16(gB[c] + k0, lB[c]);
        }
        __syncthreads();
#pragma unroll
        for (int ks = 0; ks < 2; ks++) {
            bf16x8 af[4], bfr[4];
#pragma unroll
            for (int i = 0; i < 4; i++)
                af[i] = *(const bf16x8*)&As[(wm * 64 + i * 16 + row16) * 64 + ks * 32 + q8];
#pragma unroll
            for (int j = 0; j < 4; j++)
                bfr[j] = *(const bf16x8*)&Bs[(wn * 64 + j * 16 + row16) * 64 + ks * 32 + q8];
#pragma unroll
            for (int i = 0; i < 4; i++)
#pragma unroll
                for (int j = 0; j < 4; j++)
                    acc[i][j] = __builtin_amdgcn_mfma_f32_16x16x32_bf16(af[i], bfr[j], acc[i][j], 0, 0, 0);
        }
        __syncthreads();
    }

    // epilogue: +bias -> bf16 stage -> 16B stores into y[slot]
    int quad = lane >> 4, col16 = lane & 15;
    for (int p = 0; p < 2; p++) {
        __syncthreads();
        if (wm == p) {
            for (int j = 0; j < 4; j++) {
                int n = n0 + wn * 64 + j * 16 + col16;
                float bias = b2[e * D_MODEL + n];
                for (int i = 0; i < 4; i++)
                    for (int r = 0; r < 4; r++) {
                        float v = acc[i][j][r] + bias;
                        stage[(i * 16 + quad * 4 + r) * 136 + wn * 64 + j * 16 + col16] = f2bf(v);
                    }
            }
        }
        __syncthreads();
        int row = tid >> 4, coff = (tid & 15) * 8;
        for (int rr = row; rr < 64; rr += 16) {
            int slot = slot0 + p * 64 + rr;
            if (slot < end)
                *(ushort8*)&y[(size_t)slot * D_MODEL + n0 + coff] =
                    *(const ushort8*)&stage[rr * 136 + coff];
        }
    }
}

// -------- combine: out[t] = w0*y[s0] + w1*y[s1] --------
__global__ __launch_bounds__(256) void combine_kernel(
    const unsigned short* __restrict__ y, const int* __restrict__ inv,
    const float* __restrict__ rw, float* __restrict__ out)
{
    int wave = threadIdx.x >> 6, lane = threadIdx.x & 63;
    int t = blockIdx.x * 4 + wave;
    int s0 = inv[2 * t], s1 = inv[2 * t + 1];
    float w0 = rw[2 * t], w1 = rw[2 * t + 1];
    const unsigned short* y0 = y + (size_t)s0 * D_MODEL;
    const unsigned short* y1 = y + (size_t)s1 * D_MODEL;
    float* orow = out + (size_t)t * D_MODEL;
    int c = lane * 16;
    for (int hh = 0; hh < 2; hh++) {
        ushort8 a = *(const ushort8*)&y0[c + hh * 8];
        ushort8 b = *(const ushort8*)&y1[c + hh * 8];
        float4 o0, o1;
        o0.x = w0 * bf2f(a[0]) + w1 * bf2f(b[0]);
        o0.y = w0 * bf2f(a[1]) + w1 * bf2f(b[1]);
        o0.z = w0 * bf2f(a[2]) + w1 * bf2f(b[2]);
        o0.w = w0 * bf2f(a[3]) + w1 * bf2f(b[3]);
        o1.x = w0 * bf2f(a[4]) + w1 * bf2f(b[4]);
        o1.y = w0 * bf2f(a[5]) + w1 * bf2f(b[5]);
        o1.z = w0 * bf2f(a[6]) + w1 * bf2f(b[6]);
        o1.w = w0 * bf2f(a[7]) + w1 * bf2f(b[7]);
        *(float4*)&orow[c + hh * 8]     = o0;
        *(float4*)&orow[c + hh * 8 + 4] = o1;
    }
}

// ---------------- launch ----------------
extern "C" void kernel_launch(void* const* d_in, const int* in_sizes, int n_in,
                              void* d_out, int out_size, void* d_ws, size_t ws_size,
                              hipStream_t stream)
{
    const float* x      = (const float*)d_in[0];
    const float* gate_w = (const float*)d_in[1];
    const float* w1     = (const float*)d_in[2];
    const float* b1     = (const float*)d_in[3];
    const float* w2     = (const float*)d_in[4];
    const float* b2     = (const float*)d_in[5];
    float* out = (float*)d_out;

    char* ws = (char*)d_ws;
    size_t o = 0;
    auto alloc = [&](size_t bytes) { void* p = ws + o; o += (bytes + 255) & ~(size_t)255; return p; };
    int*   cnt        = (int*)alloc(32);
    int*   cnt2       = (int*)alloc(32);
    int*   off        = (int*)alloc(64);
    int*   route_pack = (int*)alloc((size_t)T_TOKENS * 4);
    float* route_w    = (float*)alloc((size_t)T_TOKENS * 8);
    int*   tok_id     = (int*)alloc((size_t)N_SLOTS * 4);
    int*   inv        = (int*)alloc((size_t)T_TOKENS * 8);
    unsigned short* xb  = (unsigned short*)alloc((size_t)T_TOKENS * D_MODEL * 2);
    unsigned short* w1t = (unsigned short*)alloc((size_t)N_EXPERTS * D_MODEL * D_HIDDEN * 2);
    unsigned short* w2t = (unsigned short*)alloc((size_t)N_EXPERTS * D_MODEL * D_HIDDEN * 2);
    unsigned short* h   = (unsigned short*)alloc((size_t)N_SLOTS * D_HIDDEN * 2);
    // y aliases w1t (dead after gemm1): 16384*1024*2 = 33.5 MB <= 67 MB
    unsigned short* y   = w1t;

    hipMemsetAsync(cnt, 0, 32, stream);

    gate_kernel<<<T_TOKENS / 16, 256, 0, stream>>>(x, gate_w, xb, route_pack, route_w, cnt);
    offsets_kernel<<<1, 64, 0, stream>>>(cnt, off, cnt2);
    scatter_kernel<<<T_TOKENS / 64, 64, 0, stream>>>(route_pack, off, cnt2, tok_id, inv);
    transpose_convert_kernel<D_MODEL, D_HIDDEN>
        <<<dim3(D_HIDDEN / 64, D_MODEL / 64, N_EXPERTS), dim3(256), 0, stream>>>(w1, w1t);
    transpose_convert_kernel<D_HIDDEN, D_MODEL>
        <<<dim3(D_MODEL / 64, D_HIDDEN / 64, N_EXPERTS), dim3(256), 0, stream>>>(w2, w2t);
    gemm1_kernel<<<dim3(MAX_TILES, D_HIDDEN / 128), 256, 0, stream>>>(xb, w1t, b1, tok_id, off, h);
    gemm2_kernel<<<dim3(MAX_TILES, D_MODEL / 128), 256, 0, stream>>>(h, w2t, b2, off, y);
    combine_kernel<<<T_TOKENS / 4, 256, 0, stream>>>(y, inv, route_w, out);
}

// Round 2
// 773.151 us; speedup vs baseline: 1.1668x; 1.1668x over previous
//
#include <hip/hip_runtime.h>
#include <stdint.h>

#define D_MODEL   1024
#define N_EXPERTS 8
#define D_HIDDEN  4096
#define T_TOKENS  8192
#define N_SLOTS   (T_TOKENS * 2)
#define MAX_TILES 136   // sum_e ceil(n_e/128) <= 16384/128 + 7 = 135

typedef __bf16 bf16x8 __attribute__((ext_vector_type(8)));
typedef float  f32x4  __attribute__((ext_vector_type(4)));
typedef unsigned short ushort8 __attribute__((ext_vector_type(8)));

__device__ __forceinline__ unsigned short f2bf(float f) {
    unsigned int u = __float_as_uint(f);
    u += 0x7fffu + ((u >> 16) & 1u);   // round-to-nearest-even
    return (unsigned short)(u >> 16);
}
__device__ __forceinline__ float bf2f(unsigned short v) {
    return __uint_as_float((unsigned int)v << 16);
}

__device__ __forceinline__ void gl_lds16(const void* g, void* l) {
    __builtin_amdgcn_global_load_lds(
        (const __attribute__((address_space(1))) unsigned int*)g,
        (__attribute__((address_space(3))) unsigned int*)l, 16, 0, 0);
}

// ------- gating: logits -> top2 -> softmax -> counts; also converts x->bf16 -------
__global__ __launch_bounds__(256) void gate_kernel(
    const float* __restrict__ x, const float* __restrict__ gw,
    unsigned short* __restrict__ xb,
    int* __restrict__ route_pack, float* __restrict__ route_w,
    int* __restrict__ cnt)
{
    __shared__ float gws[N_EXPERTS * D_MODEL];
    __shared__ int hist[N_EXPERTS];
    int tid = threadIdx.x;
    for (int i = tid * 4; i < N_EXPERTS * D_MODEL; i += 256 * 4)
        *(float4*)&gws[i] = *(const float4*)&gw[i];
    if (tid < N_EXPERTS) hist[tid] = 0;
    __syncthreads();

    int wave = tid >> 6, lane = tid & 63;
    for (int tt = 0; tt < 4; tt++) {
        int t = blockIdx.x * 16 + wave * 4 + tt;
        const float* xr = x + (size_t)t * D_MODEL;

        float acc[N_EXPERTS];
        for (int e = 0; e < N_EXPERTS; e++) acc[e] = 0.f;
        for (int i = 0; i < 4; i++) {
            float4 xv = *(const float4*)&xr[lane * 4 + i * 256];
            ushort4 o;
            o.x = f2bf(xv.x); o.y = f2bf(xv.y); o.z = f2bf(xv.z); o.w = f2bf(xv.w);
            *(ushort4*)&xb[(size_t)t * D_MODEL + lane * 4 + i * 256] = o;
            for (int e = 0; e < N_EXPERTS; e++) {
                float4 gv = *(const float4*)&gws[e * D_MODEL + lane * 4 + i * 256];
                acc[e] += xv.x * gv.x + xv.y * gv.y + xv.z * gv.z + xv.w * gv.w;
            }
        }
        for (int e = 0; e < N_EXPERTS; e++)
            for (int off = 32; off >= 1; off >>= 1)
                acc[e] += __shfl_xor(acc[e], off, 64);

        if (lane == 0) {
            int e0 = 0; float v0 = acc[0];
            for (int e = 1; e < N_EXPERTS; e++) if (acc[e] > v0) { v0 = acc[e]; e0 = e; }
            int e1 = (e0 == 0) ? 1 : 0; float v1 = acc[e1];
            for (int e = 0; e < N_EXPERTS; e++)
                if (e != e0 && acc[e] > v1) { v1 = acc[e]; e1 = e; }
            float w0 = 1.f / (1.f + __expf(v1 - v0));
            route_pack[t] = e0 | (e1 << 8);
            route_w[2 * t]     = w0;
            route_w[2 * t + 1] = 1.f - w0;
            atomicAdd(&hist[e0], 1);
            atomicAdd(&hist[e1], 1);
        }
    }
    __syncthreads();
    if (tid < N_EXPERTS) atomicAdd(&cnt[tid], hist[tid]);
}

__global__ void offsets_kernel(const int* __restrict__ cnt,
                               int* __restrict__ off, int* __restrict__ cnt2)
{
    if (threadIdx.x == 0) {
        int a = 0;
        for (int e = 0; e < N_EXPERTS; e++) { off[e] = a; a += cnt[e]; cnt2[e] = 0; }
        off[N_EXPERTS] = a;
    }
}

// ------- scatter via wave ballot-ranking -------
__global__ __launch_bounds__(64) void scatter_kernel(
    const int* __restrict__ route_pack, const int* __restrict__ off,
    int* __restrict__ cnt2, int* __restrict__ tok_id, int* __restrict__ inv)
{
    int lane = threadIdx.x;
    int t = blockIdx.x * 64 + lane;
    int p  = route_pack[t];
    int e0 = p & 0xff, e1 = (p >> 8) & 0xff;

    unsigned long long m0[N_EXPERTS], m1[N_EXPERTS];
    for (int e = 0; e < N_EXPERTS; e++) {
        m0[e] = __ballot(e0 == e);
        m1[e] = __ballot(e1 == e);
    }
    int mybase = 0;
    if (lane < N_EXPERTS)
        mybase = atomicAdd(&cnt2[lane], __popcll(m0[lane]) + __popcll(m1[lane]));

    unsigned long long lt = (1ull << lane) - 1ull;
    int b0 = __shfl(mybase, e0);
    int s0 = off[e0] + b0 + (int)__popcll(m0[e0] & lt);
    int b1 = __shfl(mybase, e1);
    int s1 = off[e1] + b1 + (int)__popcll(m0[e1]) + (int)__popcll(m1[e1] & lt);

    tok_id[s0] = t;
    tok_id[s1] = t;
    inv[2 * t]     = s0;
    inv[2 * t + 1] = s1;
}

// src: [E][R][C] fp32  ->  dst: [E][C][R] bf16   (64x64 tiles, 16B-coalesced)
template <int R, int C>
__global__ __launch_bounds__(256) void transpose_convert_kernel(
    const float* __restrict__ src, unsigned short* __restrict__ dst)
{
    __shared__ float tile[64 * 68];
    int e = blockIdx.z;
    const float* s = src + (size_t)e * R * C;
    unsigned short* d = dst + (size_t)e * R * C;
    int r0 = blockIdx.y * 64, c0 = blockIdx.x * 64;
    int t = threadIdx.x;
    {
        int r = t >> 4, c4 = (t & 15) * 4;
        for (int p = 0; p < 4; p++, r += 16)
            *(float4*)&tile[r * 68 + c4] = *(const float4*)&s[(size_t)(r0 + r) * C + c0 + c4];
    }
    __syncthreads();
    {
        int c = t >> 2, rblk = (t & 3) * 8;
        for (int q = 0; q < 2; q++) {
            int rr = q * 32 + rblk;
            ushort8 o;
            for (int j = 0; j < 8; j++) o[j] = f2bf(tile[(rr + j) * 68 + c]);
            *(ushort8*)&d[(size_t)(c0 + c) * R + r0 + rr] = o;
        }
    }
}

// ---------------- grouped GEMM1: h = relu(x[tok] @ w1 + b1) ----------------
// 128x128 tile, BK=64, double-buffered LDS (T3-min), source-side XOR swizzle (T2),
// bijective XCD swizzle on flattened grid (T1).
__global__ __launch_bounds__(256) void gemm1_kernel(
    const unsigned short* __restrict__ xb, const unsigned short* __restrict__ w1t,
    const float* __restrict__ b1, const int* __restrict__ tok_id,
    const int* __restrict__ off, unsigned short* __restrict__ h)
{
    constexpr int NT = D_HIDDEN / 128;        // 32 n-tiles
    constexpr int BUF = 128 * 64;             // shorts per operand tile (16 KB)
    __shared__ unsigned short smem[2 * 2 * BUF];   // buf{0,1} x (As,Bs) = 64 KB
    unsigned short* stage = smem;

    // T1: bijective XCD swizzle (nwg = 136*32 = 4352, %8 == 0), N-fastest decomp
    int wg = blockIdx.x;
    int sz = (wg & 7) * ((MAX_TILES * NT) >> 3) + (wg >> 3);
    int bx = sz >> 5;                  // / NT
    int n0 = (sz & (NT - 1)) * 128;

    int e = -1, slot0 = 0, end = 0;
    {
        int acc = 0;
        for (int i = 0; i < N_EXPERTS; i++) {
            int s = off[i], en = off[i + 1];
            int nt = (en - s + 127) >> 7;
            if (e < 0 && bx < acc + nt) { e = i; slot0 = s + (bx - acc) * 128; end = en; }
            acc += nt;
        }
        if (e < 0) return;
    }
    int tid = threadIdx.x, wave = tid >> 6, lane = tid & 63;
    int lr = lane >> 3, lc = lane & 7;
    int lcs = lc ^ lr;                 // T2: source-side chunk swizzle

    f32x4 acc[4][4];
    const f32x4 zero = {0.f, 0.f, 0.f, 0.f};
    for (int i = 0; i < 4; i++) for (int j = 0; j < 4; j++) acc[i][j] = zero;

    const unsigned short* gA[4];
    const unsigned short* gB[4];
    int ldsA[4], ldsB[4];
#pragma unroll
    for (int c = 0; c < 4; c++) {
        int arow = wave * 32 + c * 8 + lr;
        int slot = min(slot0 + arow, end - 1);
        gA[c] = xb + (size_t)tok_id[slot] * D_MODEL + lcs * 8;
        gB[c] = w1t + ((size_t)e * D_HIDDEN + n0 + arow) * D_MODEL + lcs * 8;
        ldsA[c] = (wave * 32 + c * 8) * 64;
        ldsB[c] = BUF + (wave * 32 + c * 8) * 64;
    }

    int wm = wave & 1, wn = wave >> 1;
    int row16 = lane & 15, q4 = lane >> 4;
    int sx = row16 & 7;                // T2: read-side chunk XOR

    // prologue: stage K-tile 0 into buf 0
#pragma unroll
    for (int c = 0; c < 4; c++) {
        gl_lds16(gA[c], smem + ldsA[c]);
        gl_lds16(gB[c], smem + ldsB[c]);
    }
    __syncthreads();

    int cur = 0;
    for (int t = 0; t < D_MODEL / 64; t++) {
        if (t + 1 < D_MODEL / 64) {          // issue next-tile stage FIRST (overlap)
            int k0 = (t + 1) * 64;
            unsigned short* dst = smem + (cur ^ 1) * 2 * BUF;
#pragma unroll
            for (int c = 0; c < 4; c++) {
                gl_lds16(gA[c] + k0, dst + ldsA[c]);
                gl_lds16(gB[c] + k0, dst + ldsB[c]);
            }
        }
        const unsigned short* As = smem + cur * 2 * BUF;
        const unsigned short* Bs = As + BUF;
#pragma unroll
        for (int ks = 0; ks < 2; ks++) {
            bf16x8 af[4], bfr[4];
#pragma unroll
            for (int i = 0; i < 4; i++)
                af[i] = *(const bf16x8*)&As[(wm * 64 + i * 16 + row16) * 64 + (((ks * 4 + q4) ^ sx) * 8)];
#pragma unroll
            for (int j = 0; j < 4; j++)
                bfr[j] = *(const bf16x8*)&Bs[(wn * 64 + j * 16 + row16) * 64 + (((ks * 4 + q4) ^ sx) * 8)];
#pragma unroll
            for (int i = 0; i < 4; i++)
#pragma unroll
                for (int j = 0; j < 4; j++)
                    acc[i][j] = __builtin_amdgcn_mfma_f32_16x16x32_bf16(af[i], bfr[j], acc[i][j], 0, 0, 0);
        }
        __syncthreads();
        cur ^= 1;
    }

    // epilogue: bias+relu -> bf16 stage in LDS (64x128, stride 136) -> 16B stores
    int quad = lane >> 4, col16 = lane & 15;
    for (int p = 0; p < 2; p++) {
        __syncthreads();
        if (wm == p) {
            for (int j = 0; j < 4; j++) {
                int n = n0 + wn * 64 + j * 16 + col16;
                float bias = b1[e * D_HIDDEN + n];
                for (int i = 0; i < 4; i++)
                    for (int r = 0; r < 4; r++) {
                        float v = acc[i][j][r] + bias;
                        v = v > 0.f ? v : 0.f;
                        stage[(i * 16 + quad * 4 + r) * 136 + wn * 64 + j * 16 + col16] = f2bf(v);
                    }
            }
        }
        __syncthreads();
        int row = tid >> 4, coff = (tid & 15) * 8;
        for (int rr = row; rr < 64; rr += 16) {
            int slot = slot0 + p * 64 + rr;
            if (slot < end)
                *(ushort8*)&h[(size_t)slot * D_HIDDEN + n0 + coff] =
                    *(const ushort8*)&stage[rr * 136 + coff];
        }
    }
}

// -------- grouped GEMM2: y[slot] = h[slot] @ w2 + b2 --------
__global__ __launch_bounds__(256) void gemm2_kernel(
    const unsigned short* __restrict__ h, const unsigned short* __restrict__ w2t,
    const float* __restrict__ b2, const int* __restrict__ off,
    unsigned short* __restrict__ y)
{
    constexpr int NT = D_MODEL / 128;         // 8 n-tiles
    constexpr int BUF = 128 * 64;
    __shared__ unsigned short smem[2 * 2 * BUF];
    unsigned short* stage = smem;

    int wg = blockIdx.x;
    int sz = (wg & 7) * ((MAX_TILES * NT) >> 3) + (wg >> 3);
    int bx = sz >> 3;                  // / NT
    int n0 = (sz & (NT - 1)) * 128;

    int e = -1, slot0 = 0, end = 0;
    {
        int acc = 0;
        for (int i = 0; i < N_EXPERTS; i++) {
            int s = off[i], en = off[i + 1];
            int nt = (en - s + 127) >> 7;
            if (e < 0 && bx < acc + nt) { e = i; slot0 = s + (bx - acc) * 128; end = en; }
            acc += nt;
        }
        if (e < 0) return;
    }
    int tid = threadIdx.x, wave = tid >> 6, lane = tid & 63;
    int lr = lane >> 3, lc = lane & 7;
    int lcs = lc ^ lr;

    f32x4 acc[4][4];
    const f32x4 zero = {0.f, 0.f, 0.f, 0.f};
    for (int i = 0; i < 4; i++) for (int j = 0; j < 4; j++) acc[i][j] = zero;

    const unsigned short* gA[4];
    const unsigned short* gB[4];
    int ldsA[4], ldsB[4];
#pragma unroll
    for (int c = 0; c < 4; c++) {
        int arow = wave * 32 + c * 8 + lr;
        int slot = min(slot0 + arow, end - 1);
        gA[c] = h + (size_t)slot * D_HIDDEN + lcs * 8;
        gB[c] = w2t + ((size_t)e * D_MODEL + n0 + arow) * D_HIDDEN + lcs * 8;
        ldsA[c] = (wave * 32 + c * 8) * 64;
        ldsB[c] = BUF + (wave * 32 + c * 8) * 64;
    }

    int wm = wave & 1, wn = wave >> 1;
    int row16 = lane & 15, q4 = lane >> 4;
    int sx = row16 & 7;

#pragma unroll
    for (int c = 0; c < 4; c++) {
        gl_lds16(gA[c], smem + ldsA[c]);
        gl_lds16(gB[c], smem + ldsB[c]);
    }
    __syncthreads();

    int cur = 0;
    for (int t = 0; t < D_HIDDEN / 64; t++) {
        if (t + 1 < D_HIDDEN / 64) {
            int k0 = (t + 1) * 64;
            unsigned short* dst = smem + (cur ^ 1) * 2 * BUF;
#pragma unroll
            for (int c = 0; c < 4; c++) {
                gl_lds16(gA[c] + k0, dst + ldsA[c]);
                gl_lds16(gB[c] + k0, dst + ldsB[c]);
            }
        }
        const unsigned short* As = smem + cur * 2 * BUF;
        const unsigned short* Bs = As + BUF;
#pragma unroll
        for (int ks = 0; ks < 2; ks++) {
            bf16x8 af[4], bfr[4];
#pragma unroll
            for (int i = 0; i < 4; i++)
                af[i] = *(const bf16x8*)&As[(wm * 64 + i * 16 + row16) * 64 + (((ks * 4 + q4) ^ sx) * 8)];
#pragma unroll
            for (int j = 0; j < 4; j++)
                bfr[j] = *(const bf16x8*)&Bs[(wn * 64 + j * 16 + row16) * 64 + (((ks * 4 + q4) ^ sx) * 8)];
#pragma unroll
            for (int i = 0; i < 4; i++)
#pragma unroll
                for (int j = 0; j < 4; j++)
                    acc[i][j] = __builtin_amdgcn_mfma_f32_16x16x32_bf16(af[i], bfr[j], acc[i][j], 0, 0, 0);
        }
        __syncthreads();
        cur ^= 1;
    }

    // epilogue: +bias -> bf16 stage -> 16B stores into y[slot]
    int quad = lane >> 4, col16 = lane & 15;
    for (int p = 0; p < 2; p++) {
        __syncthreads();
        if (wm == p) {
            for (int j = 0; j < 4; j++) {
                int n = n0 + wn * 64 + j * 16 + col16;
                float bias = b2[e * D_MODEL + n];
                for (int i = 0; i < 4; i++)
                    for (int r = 0; r < 4; r++) {
                        float v = acc[i][j][r] + bias;
                        stage[(i * 16 + quad * 4 + r) * 136 + wn * 64 + j * 16 + col16] = f2bf(v);
                    }
            }
        }
        __syncthreads();
        int row = tid >> 4, coff = (tid & 15) * 8;
        for (int rr = row; rr < 64; rr += 16) {
            int slot = slot0 + p * 64 + rr;
            if (slot < end)
                *(ushort8*)&y[(size_t)slot * D_MODEL + n0 + coff] =
                    *(const ushort8*)&stage[rr * 136 + coff];
        }
    }
}

// -------- combine: out[t] = w0*y[s0] + w1*y[s1] --------
__global__ __launch_bounds__(256) void combine_kernel(
    const unsigned short* __restrict__ y, const int* __restrict__ inv,
    const float* __restrict__ rw, float* __restrict__ out)
{
    int wave = threadIdx.x >> 6, lane = threadIdx.x & 63;
    int t = blockIdx.x * 4 + wave;
    int s0 = inv[2 * t], s1 = inv[2 * t + 1];
    float w0 = rw[2 * t], w1 = rw[2 * t + 1];
    const unsigned short* y0 = y + (size_t)s0 * D_MODEL;
    const unsigned short* y1 = y + (size_t)s1 * D_MODEL;
    float* orow = out + (size_t)t * D_MODEL;
    int c = lane * 16;
    for (int hh = 0; hh < 2; hh++) {
        ushort8 a = *(const ushort8*)&y0[c + hh * 8];
        ushort8 b = *(const ushort8*)&y1[c + hh * 8];
        float4 o0, o1;
        o0.x = w0 * bf2f(a[0]) + w1 * bf2f(b[0]);
        o0.y = w0 * bf2f(a[1]) + w1 * bf2f(b[1]);
        o0.z = w0 * bf2f(a[2]) + w1 * bf2f(b[2]);
        o0.w = w0 * bf2f(a[3]) + w1 * bf2f(b[3]);
        o1.x = w0 * bf2f(a[4]) + w1 * bf2f(b[4]);
        o1.y = w0 * bf2f(a[5]) + w1 * bf2f(b[5]);
        o1.z = w0 * bf2f(a[6]) + w1 * bf2f(b[6]);
        o1.w = w0 * bf2f(a[7]) + w1 * bf2f(b[7]);
        *(float4*)&orow[c + hh * 8]     = o0;
        *(float4*)&orow[c + hh * 8 + 4] = o1;
    }
}

// ---------------- launch ----------------
extern "C" void kernel_launch(void* const* d_in, const int* in_sizes, int n_in,
                              void* d_out, int out_size, void* d_ws, size_t ws_size,
                              hipStream_t stream)
{
    const float* x      = (const float*)d_in[0];
    const float* gate_w = (const float*)d_in[1];
    const float* w1     = (const float*)d_in[2];
    const float* b1     = (const float*)d_in[3];
    const float* w2     = (const float*)d_in[4];
    const float* b2     = (const float*)d_in[5];
    float* out = (float*)d_out;

    char* ws = (char*)d_ws;
    size_t o = 0;
    auto alloc = [&](size_t bytes) { void* p = ws + o; o += (bytes + 255) & ~(size_t)255; return p; };
    int*   cnt        = (int*)alloc(32);
    int*   cnt2       = (int*)alloc(32);
    int*   off        = (int*)alloc(64);
    int*   route_pack = (int*)alloc((size_t)T_TOKENS * 4);
    float* route_w    = (float*)alloc((size_t)T_TOKENS * 8);
    int*   tok_id     = (int*)alloc((size_t)N_SLOTS * 4);
    int*   inv        = (int*)alloc((size_t)T_TOKENS * 8);
    unsigned short* xb  = (unsigned short*)alloc((size_t)T_TOKENS * D_MODEL * 2);
    unsigned short* w1t = (unsigned short*)alloc((size_t)N_EXPERTS * D_MODEL * D_HIDDEN * 2);
    unsigned short* w2t = (unsigned short*)alloc((size_t)N_EXPERTS * D_MODEL * D_HIDDEN * 2);
    unsigned short* h   = (unsigned short*)alloc((size_t)N_SLOTS * D_HIDDEN * 2);
    // y aliases w1t (dead after gemm1)
    unsigned short* y   = w1t;

    hipMemsetAsync(cnt, 0, 32, stream);

    gate_kernel<<<T_TOKENS / 16, 256, 0, stream>>>(x, gate_w, xb, route_pack, route_w, cnt);
    offsets_kernel<<<1, 64, 0, stream>>>(cnt, off, cnt2);
    scatter_kernel<<<T_TOKENS / 64, 64, 0, stream>>>(route_pack, off, cnt2, tok_id, inv);
    transpose_convert_kernel<D_MODEL, D_HIDDEN>
        <<<dim3(D_HIDDEN / 64, D_MODEL / 64, N_EXPERTS), dim3(256), 0, stream>>>(w1, w1t);
    transpose_convert_kernel<D_HIDDEN, D_MODEL>
        <<<dim3(D_MODEL / 64, D_HIDDEN / 64, N_EXPERTS), dim3(256), 0, stream>>>(w2, w2t);
    gemm1_kernel<<<dim3(MAX_TILES * (D_HIDDEN / 128)), 256, 0, stream>>>(xb, w1t, b1, tok_id, off, h);
    gemm2_kernel<<<dim3(MAX_TILES * (D_MODEL / 128)), 256, 0, stream>>>(h, w2t, b2, off, y);
    combine_kernel<<<T_TOKENS / 4, 256, 0, stream>>>(y, inv, route_w, out);
}

// Round 4
// 744.595 us; speedup vs baseline: 1.2115x; 1.0384x over previous
//
#include <hip/hip_runtime.h>
#include <stdint.h>

#define D_MODEL   1024
#define N_EXPERTS 8
#define D_HIDDEN  4096
#define T_TOKENS  8192
#define N_SLOTS   (T_TOKENS * 2)
#define MAX_MT    71    // sum_e ceil(n_e/256) <= 16384/256 + 7 = 71

typedef __bf16 bf16x8 __attribute__((ext_vector_type(8)));
typedef float  f32x4  __attribute__((ext_vector_type(4)));
typedef unsigned short ushort8 __attribute__((ext_vector_type(8)));

__device__ __forceinline__ unsigned short f2bf(float f) {
    unsigned int u = __float_as_uint(f);
    u += 0x7fffu + ((u >> 16) & 1u);   // round-to-nearest-even
    return (unsigned short)(u >> 16);
}
__device__ __forceinline__ float bf2f(unsigned short v) {
    return __uint_as_float((unsigned int)v << 16);
}

__device__ __forceinline__ void gl_lds16(const void* g, void* l) {
    __builtin_amdgcn_global_load_lds(
        (const __attribute__((address_space(1))) unsigned int*)g,
        (__attribute__((address_space(3))) unsigned int*)l, 16, 0, 0);
}

// ------- gating: logits -> top2 -> softmax -> counts; also converts x->bf16 -------
__global__ __launch_bounds__(256) void gate_kernel(
    const float* __restrict__ x, const float* __restrict__ gw,
    unsigned short* __restrict__ xb,
    int* __restrict__ route_pack, float* __restrict__ route_w,
    int* __restrict__ cnt)
{
    __shared__ float gws[N_EXPERTS * D_MODEL];
    __shared__ int hist[N_EXPERTS];
    int tid = threadIdx.x;
    for (int i = tid * 4; i < N_EXPERTS * D_MODEL; i += 256 * 4)
        *(float4*)&gws[i] = *(const float4*)&gw[i];
    if (tid < N_EXPERTS) hist[tid] = 0;
    __syncthreads();

    int wave = tid >> 6, lane = tid & 63;
    for (int tt = 0; tt < 4; tt++) {
        int t = blockIdx.x * 16 + wave * 4 + tt;
        const float* xr = x + (size_t)t * D_MODEL;

        float acc[N_EXPERTS];
        for (int e = 0; e < N_EXPERTS; e++) acc[e] = 0.f;
        for (int i = 0; i < 4; i++) {
            float4 xv = *(const float4*)&xr[lane * 4 + i * 256];
            ushort4 o;
            o.x = f2bf(xv.x); o.y = f2bf(xv.y); o.z = f2bf(xv.z); o.w = f2bf(xv.w);
            *(ushort4*)&xb[(size_t)t * D_MODEL + lane * 4 + i * 256] = o;
            for (int e = 0; e < N_EXPERTS; e++) {
                float4 gv = *(const float4*)&gws[e * D_MODEL + lane * 4 + i * 256];
                acc[e] += xv.x * gv.x + xv.y * gv.y + xv.z * gv.z + xv.w * gv.w;
            }
        }
        for (int e = 0; e < N_EXPERTS; e++)
            for (int off = 32; off >= 1; off >>= 1)
                acc[e] += __shfl_xor(acc[e], off, 64);

        if (lane == 0) {
            int e0 = 0; float v0 = acc[0];
            for (int e = 1; e < N_EXPERTS; e++) if (acc[e] > v0) { v0 = acc[e]; e0 = e; }
            int e1 = (e0 == 0) ? 1 : 0; float v1 = acc[e1];
            for (int e = 0; e < N_EXPERTS; e++)
                if (e != e0 && acc[e] > v1) { v1 = acc[e]; e1 = e; }
            float w0 = 1.f / (1.f + __expf(v1 - v0));
            route_pack[t] = e0 | (e1 << 8);
            route_w[2 * t]     = w0;
            route_w[2 * t + 1] = 1.f - w0;
            atomicAdd(&hist[e0], 1);
            atomicAdd(&hist[e1], 1);
        }
    }
    __syncthreads();
    if (tid < N_EXPERTS) atomicAdd(&cnt[tid], hist[tid]);
}

__global__ void offsets_kernel(const int* __restrict__ cnt,
                               int* __restrict__ off, int* __restrict__ cnt2)
{
    if (threadIdx.x == 0) {
        int a = 0;
        for (int e = 0; e < N_EXPERTS; e++) { off[e] = a; a += cnt[e]; cnt2[e] = 0; }
        off[N_EXPERTS] = a;
    }
}

// ------- scatter via wave ballot-ranking -------
__global__ __launch_bounds__(64) void scatter_kernel(
    const int* __restrict__ route_pack, const int* __restrict__ off,
    int* __restrict__ cnt2, int* __restrict__ tok_id, int* __restrict__ inv)
{
    int lane = threadIdx.x;
    int t = blockIdx.x * 64 + lane;
    int p  = route_pack[t];
    int e0 = p & 0xff, e1 = (p >> 8) & 0xff;

    unsigned long long m0[N_EXPERTS], m1[N_EXPERTS];
    for (int e = 0; e < N_EXPERTS; e++) {
        m0[e] = __ballot(e0 == e);
        m1[e] = __ballot(e1 == e);
    }
    int mybase = 0;
    if (lane < N_EXPERTS)
        mybase = atomicAdd(&cnt2[lane], __popcll(m0[lane]) + __popcll(m1[lane]));

    unsigned long long lt = (1ull << lane) - 1ull;
    int b0 = __shfl(mybase, e0);
    int s0 = off[e0] + b0 + (int)__popcll(m0[e0] & lt);
    int b1 = __shfl(mybase, e1);
    int s1 = off[e1] + b1 + (int)__popcll(m0[e1]) + (int)__popcll(m1[e1] & lt);

    tok_id[s0] = t;
    tok_id[s1] = t;
    inv[2 * t]     = s0;
    inv[2 * t + 1] = s1;
}

// src: [E][R][C] fp32  ->  dst: [E][C][R] bf16   (64x64 tiles, 16B-coalesced)
template <int R, int C>
__global__ __launch_bounds__(256) void transpose_convert_kernel(
    const float* __restrict__ src, unsigned short* __restrict__ dst)
{
    __shared__ float tile[64 * 68];
    int e = blockIdx.z;
    const float* s = src + (size_t)e * R * C;
    unsigned short* d = dst + (size_t)e * R * C;
    int r0 = blockIdx.y * 64, c0 = blockIdx.x * 64;
    int t = threadIdx.x;
    {
        int r = t >> 4, c4 = (t & 15) * 4;
        for (int p = 0; p < 4; p++, r += 16)
            *(float4*)&tile[r * 68 + c4] = *(const float4*)&s[(size_t)(r0 + r) * C + c0 + c4];
    }
    __syncthreads();
    {
        int c = t >> 2, rblk = (t & 3) * 8;
        for (int q = 0; q < 2; q++) {
            int rr = q * 32 + rblk;
            ushort8 o;
            for (int j = 0; j < 8; j++) o[j] = f2bf(tile[(rr + j) * 68 + c]);
            *(ushort8*)&d[(size_t)(c0 + c) * R + r0 + rr] = o;
        }
    }
}

// ======== grouped GEMM: 256x128 tile, BK=64, triple-buffer counted-vmcnt pipeline ====
// 512 thr = 8 waves (2M x 4N). Per-wave output 128x32 -> acc[8][2].
// LDS: 3 bufs x (A 256x64 + B 128x64) bf16 = 144 KB.
// Iter t: stage(tile t+2 -> buf (t+2)%3) [6 gl_lds], compute buf t%3, vmcnt(6), s_barrier.
// Invariant: buf (t+2)%3 was consumed in iter t-1; every ds_read value is consumed by an
// MFMA before the end barrier (lgkmcnt), so post-barrier staging cannot race the reads.
template<int KDIM, int NC, bool RELU, bool USE_TOK>
__global__ __launch_bounds__(512, 2) void moe_gemm_kernel(
    const unsigned short* __restrict__ Ag, const unsigned short* __restrict__ Bw,
    const float* __restrict__ bias, const int* __restrict__ tok_id,
    const int* __restrict__ off, unsigned short* __restrict__ Cout)
{
    constexpr int NT   = KDIM / 64;         // K-tiles (16 or 64)
    constexpr int NTN  = NC / 128;          // N-tiles
    constexpr int NWG  = MAX_MT * NTN;
    constexpr int ASH  = 256 * 64;          // A shorts per buffer
    constexpr int BUFS = (256 + 128) * 64;  // shorts per buffer (48 KB)
    __shared__ unsigned short smem[3 * BUFS];   // 144 KB

    // T1: bijective XCD swizzle (m204). Consecutive sz share bx -> A-panel L2 reuse.
    int wg = blockIdx.x;
    constexpr int qq8 = NWG / 8, rr8 = NWG % 8;
    int xcd = wg & 7, idx = wg >> 3;
    int sz = (xcd < rr8 ? xcd * (qq8 + 1) : rr8 * (qq8 + 1) + (xcd - rr8) * qq8) + idx;
    int bx = sz / NTN;
    int n0 = (sz % NTN) * 128;

    int e = -1, slot0 = 0, end = 0;
    {
        int acc = 0;
        for (int i = 0; i < N_EXPERTS; i++) {
            int s = off[i], en = off[i + 1];
            int nt = (en - s + 255) >> 8;
            if (e < 0 && bx < acc + nt) { e = i; slot0 = s + (bx - acc) * 256; end = en; }
            acc += nt;
        }
        if (e < 0) return;
    }

    int tid = threadIdx.x, wave = tid >> 6, lane = tid & 63;
    int wm = wave >> 2, wn = wave & 3;            // 2M x 4N
    int lr = lane >> 3, lc = lane & 7;
    int lcs = lc ^ lr;                            // T2 source-side chunk swizzle
    int row16 = lane & 15, qk = lane >> 4;
    int sx = row16 & 7;                           // T2 read-side chunk XOR

    f32x4 acc[8][2];
    const f32x4 zero = {0.f, 0.f, 0.f, 0.f};
#pragma unroll
    for (int i = 0; i < 8; i++) { acc[i][0] = zero; acc[i][1] = zero; }

    // staging: wave w stages A rows [w*32, w*32+32) (4 calls) and B rows [w*16, +16) (2 calls)
    const unsigned short* gA[4];
    const unsigned short* gB[2];
    int ldsA[4], ldsB[2];
#pragma unroll
    for (int c = 0; c < 4; c++) {
        int arow = wave * 32 + c * 8 + lr;
        int slotc = min(slot0 + arow, end - 1);
        int grow;
        if constexpr (USE_TOK) grow = tok_id[slotc]; else grow = slotc;
        gA[c] = Ag + (size_t)grow * KDIM + lcs * 8;
        ldsA[c] = (wave * 32 + c * 8) * 64;
    }
#pragma unroll
    for (int c = 0; c < 2; c++) {
        int brow = wave * 16 + c * 8 + lr;
        gB[c] = Bw + ((size_t)e * NC + n0 + brow) * KDIM + lcs * 8;
        ldsB[c] = ASH + (wave * 16 + c * 8) * 64;
    }

    auto stage = [&](int b, int kt) {
        unsigned short* base = smem + b * BUFS;
#pragma unroll
        for (int c = 0; c < 4; c++) gl_lds16(gA[c] + kt * 64, base + ldsA[c]);
#pragma unroll
        for (int c = 0; c < 2; c++) gl_lds16(gB[c] + kt * 64, base + ldsB[c]);
    };

    // prologue: tiles 0,1 -> bufs 0,1; wait tile 0 (6 loads of tile 1 stay in flight)
    stage(0, 0);
    stage(1, 1);
    asm volatile("s_waitcnt vmcnt(6)" ::: "memory");
    __builtin_amdgcn_s_barrier();

    int cur = 0, nb = 2;
    for (int t = 0; t < NT; t++) {
        stage(nb, min(t + 2, NT - 1));       // tail restages NT-1 into a never-read buf
        const unsigned short* Ab = smem + cur * BUFS;
        const unsigned short* Bb = Ab + ASH;
        __builtin_amdgcn_s_setprio(1);
#pragma unroll
        for (int ks = 0; ks < 2; ks++) {
            bf16x8 af[8], bq[2];
#pragma unroll
            for (int i = 0; i < 8; i++) {
                int rr = wm * 128 + i * 16 + row16;
                af[i] = *(const bf16x8*)&Ab[rr * 64 + (((ks * 4 + qk) ^ sx) * 8)];
            }
#pragma unroll
            for (int j = 0; j < 2; j++) {
                int br = wn * 32 + j * 16 + row16;
                bq[j] = *(const bf16x8*)&Bb[br * 64 + (((ks * 4 + qk) ^ sx) * 8)];
            }
#pragma unroll
            for (int i = 0; i < 8; i++)
#pragma unroll
                for (int j = 0; j < 2; j++)
                    acc[i][j] = __builtin_amdgcn_mfma_f32_16x16x32_bf16(af[i], bq[j], acc[i][j], 0, 0, 0);
        }
        __builtin_amdgcn_s_setprio(0);
        asm volatile("s_waitcnt vmcnt(6)" ::: "memory");   // tile t+1 resident; t+2 in flight
        __builtin_amdgcn_s_barrier();
        cur = (cur + 1) == 3 ? 0 : cur + 1;
        nb  = (nb + 1)  == 3 ? 0 : nb + 1;
    }

    // epilogue: drain garbage prefetches, reuse LDS to stage 128-row output halves
    asm volatile("s_waitcnt vmcnt(0) lgkmcnt(0)" ::: "memory");
    __syncthreads();
    unsigned short* stg = smem;
    int quad = lane >> 4, c16 = lane & 15;
    for (int p = 0; p < 2; p++) {
        if (p) __syncthreads();
        if (wm == p) {
#pragma unroll
            for (int j = 0; j < 2; j++) {
                int n = n0 + wn * 32 + j * 16 + c16;
                float bv = bias[e * NC + n];
#pragma unroll
                for (int i = 0; i < 8; i++)
#pragma unroll
                    for (int r = 0; r < 4; r++) {
                        float v = acc[i][j][r] + bv;
                        if (RELU) v = v > 0.f ? v : 0.f;
                        stg[(i * 16 + quad * 4 + r) * 136 + wn * 32 + j * 16 + c16] = f2bf(v);
                    }
            }
        }
        __syncthreads();
        int srow = tid >> 4, chunk = (tid & 15) * 8;
#pragma unroll
        for (int s8 = 0; s8 < 4; s8++) {
            int rr = srow + s8 * 32;
            int slot = slot0 + p * 128 + rr;
            if (slot < end)
                *(ushort8*)&Cout[(size_t)slot * NC + n0 + chunk] =
                    *(const ushort8*)&stg[rr * 136 + chunk];
        }
    }
}

// -------- combine: out[t] = w0*y[s0] + w1*y[s1] --------
__global__ __launch_bounds__(256) void combine_kernel(
    const unsigned short* __restrict__ y, const int* __restrict__ inv,
    const float* __restrict__ rw, float* __restrict__ out)
{
    int wave = threadIdx.x >> 6, lane = threadIdx.x & 63;
    int t = blockIdx.x * 4 + wave;
    int s0 = inv[2 * t], s1 = inv[2 * t + 1];
    float w0 = rw[2 * t], w1 = rw[2 * t + 1];
    const unsigned short* y0 = y + (size_t)s0 * D_MODEL;
    const unsigned short* y1 = y + (size_t)s1 * D_MODEL;
    float* orow = out + (size_t)t * D_MODEL;
    int c = lane * 16;
    for (int hh = 0; hh < 2; hh++) {
        ushort8 a = *(const ushort8*)&y0[c + hh * 8];
        ushort8 b = *(const ushort8*)&y1[c + hh * 8];
        float4 o0, o1;
        o0.x = w0 * bf2f(a[0]) + w1 * bf2f(b[0]);
        o0.y = w0 * bf2f(a[1]) + w1 * bf2f(b[1]);
        o0.z = w0 * bf2f(a[2]) + w1 * bf2f(b[2]);
        o0.w = w0 * bf2f(a[3]) + w1 * bf2f(b[3]);
        o1.x = w0 * bf2f(a[4]) + w1 * bf2f(b[4]);
        o1.y = w0 * bf2f(a[5]) + w1 * bf2f(b[5]);
        o1.z = w0 * bf2f(a[6]) + w1 * bf2f(b[6]);
        o1.w = w0 * bf2f(a[7]) + w1 * bf2f(b[7]);
        *(float4*)&orow[c + hh * 8]     = o0;
        *(float4*)&orow[c + hh * 8 + 4] = o1;
    }
}

// ---------------- launch ----------------
extern "C" void kernel_launch(void* const* d_in, const int* in_sizes, int n_in,
                              void* d_out, int out_size, void* d_ws, size_t ws_size,
                              hipStream_t stream)
{
    const float* x      = (const float*)d_in[0];
    const float* gate_w = (const float*)d_in[1];
    const float* w1     = (const float*)d_in[2];
    const float* b1     = (const float*)d_in[3];
    const float* w2     = (const float*)d_in[4];
    const float* b2     = (const float*)d_in[5];
    float* out = (float*)d_out;

    char* ws = (char*)d_ws;
    size_t o = 0;
    auto alloc = [&](size_t bytes) { void* p = ws + o; o += (bytes + 255) & ~(size_t)255; return p; };
    int*   cnt        = (int*)alloc(32);
    int*   cnt2       = (int*)alloc(32);
    int*   off        = (int*)alloc(64);
    int*   route_pack = (int*)alloc((size_t)T_TOKENS * 4);
    float* route_w    = (float*)alloc((size_t)T_TOKENS * 8);
    int*   tok_id     = (int*)alloc((size_t)N_SLOTS * 4);
    int*   inv        = (int*)alloc((size_t)T_TOKENS * 8);
    unsigned short* xb  = (unsigned short*)alloc((size_t)T_TOKENS * D_MODEL * 2);
    unsigned short* w1t = (unsigned short*)alloc((size_t)N_EXPERTS * D_MODEL * D_HIDDEN * 2);
    unsigned short* w2t = (unsigned short*)alloc((size_t)N_EXPERTS * D_MODEL * D_HIDDEN * 2);
    unsigned short* h   = (unsigned short*)alloc((size_t)N_SLOTS * D_HIDDEN * 2);
    // y aliases w1t (dead after gemm1)
    unsigned short* y   = w1t;

    hipMemsetAsync(cnt, 0, 32, stream);

    gate_kernel<<<T_TOKENS / 16, 256, 0, stream>>>(x, gate_w, xb, route_pack, route_w, cnt);
    offsets_kernel<<<1, 64, 0, stream>>>(cnt, off, cnt2);
    scatter_kernel<<<T_TOKENS / 64, 64, 0, stream>>>(route_pack, off, cnt2, tok_id, inv);
    transpose_convert_kernel<D_MODEL, D_HIDDEN>
        <<<dim3(D_HIDDEN / 64, D_MODEL / 64, N_EXPERTS), dim3(256), 0, stream>>>(w1, w1t);
    transpose_convert_kernel<D_HIDDEN, D_MODEL>
        <<<dim3(D_MODEL / 64, D_HIDDEN / 64, N_EXPERTS), dim3(256), 0, stream>>>(w2, w2t);
    moe_gemm_kernel<D_MODEL, D_HIDDEN, true, true>
        <<<dim3(MAX_MT * (D_HIDDEN / 128)), dim3(512), 0, stream>>>(xb, w1t, b1, tok_id, off, h);
    moe_gemm_kernel<D_HIDDEN, D_MODEL, false, false>
        <<<dim3(MAX_MT * (D_MODEL / 128)), dim3(512), 0, stream>>>(h, w2t, b2, tok_id, off, y);
    combine_kernel<<<T_TOKENS / 4, 256, 0, stream>>>(y, inv, route_w, out);
}

// Round 5
// 743.542 us; speedup vs baseline: 1.2132x; 1.0014x over previous
//
#include <hip/hip_runtime.h>
#include <stdint.h>

#define D_MODEL   1024
#define N_EXPERTS 8
#define D_HIDDEN  4096
#define T_TOKENS  8192
#define N_SLOTS   (T_TOKENS * 2)
#define MAX_MT    71    // sum_e ceil(n_e/256) <= 16384/256 + 7 = 71

typedef __bf16 bf16x8 __attribute__((ext_vector_type(8)));
typedef float  f32x4  __attribute__((ext_vector_type(4)));
typedef unsigned short ushort8 __attribute__((ext_vector_type(8)));

__device__ __forceinline__ unsigned short f2bf(float f) {
    unsigned int u = __float_as_uint(f);
    u += 0x7fffu + ((u >> 16) & 1u);   // round-to-nearest-even
    return (unsigned short)(u >> 16);
}
__device__ __forceinline__ float bf2f(unsigned short v) {
    return __uint_as_float((unsigned int)v << 16);
}

__device__ __forceinline__ void gl_lds16(const void* g, void* l) {
    __builtin_amdgcn_global_load_lds(
        (const __attribute__((address_space(1))) unsigned int*)g,
        (__attribute__((address_space(3))) unsigned int*)l, 16, 0, 0);
}

// ------- gating: logits -> top2 -> softmax -> counts; also converts x->bf16 -------
__global__ __launch_bounds__(256) void gate_kernel(
    const float* __restrict__ x, const float* __restrict__ gw,
    unsigned short* __restrict__ xb,
    int* __restrict__ route_pack, float* __restrict__ route_w,
    int* __restrict__ cnt)
{
    __shared__ float gws[N_EXPERTS * D_MODEL];
    __shared__ int hist[N_EXPERTS];
    int tid = threadIdx.x;
    for (int i = tid * 4; i < N_EXPERTS * D_MODEL; i += 256 * 4)
        *(float4*)&gws[i] = *(const float4*)&gw[i];
    if (tid < N_EXPERTS) hist[tid] = 0;
    __syncthreads();

    int wave = tid >> 6, lane = tid & 63;
    for (int tt = 0; tt < 4; tt++) {
        int t = blockIdx.x * 16 + wave * 4 + tt;
        const float* xr = x + (size_t)t * D_MODEL;

        float acc[N_EXPERTS];
        for (int e = 0; e < N_EXPERTS; e++) acc[e] = 0.f;
        for (int i = 0; i < 4; i++) {
            float4 xv = *(const float4*)&xr[lane * 4 + i * 256];
            ushort4 o;
            o.x = f2bf(xv.x); o.y = f2bf(xv.y); o.z = f2bf(xv.z); o.w = f2bf(xv.w);
            *(ushort4*)&xb[(size_t)t * D_MODEL + lane * 4 + i * 256] = o;
            for (int e = 0; e < N_EXPERTS; e++) {
                float4 gv = *(const float4*)&gws[e * D_MODEL + lane * 4 + i * 256];
                acc[e] += xv.x * gv.x + xv.y * gv.y + xv.z * gv.z + xv.w * gv.w;
            }
        }
        for (int e = 0; e < N_EXPERTS; e++)
            for (int off = 32; off >= 1; off >>= 1)
                acc[e] += __shfl_xor(acc[e], off, 64);

        if (lane == 0) {
            int e0 = 0; float v0 = acc[0];
            for (int e = 1; e < N_EXPERTS; e++) if (acc[e] > v0) { v0 = acc[e]; e0 = e; }
            int e1 = (e0 == 0) ? 1 : 0; float v1 = acc[e1];
            for (int e = 0; e < N_EXPERTS; e++)
                if (e != e0 && acc[e] > v1) { v1 = acc[e]; e1 = e; }
            float w0 = 1.f / (1.f + __expf(v1 - v0));
            route_pack[t] = e0 | (e1 << 8);
            route_w[2 * t]     = w0;
            route_w[2 * t + 1] = 1.f - w0;
            atomicAdd(&hist[e0], 1);
            atomicAdd(&hist[e1], 1);
        }
    }
    __syncthreads();
    if (tid < N_EXPERTS) atomicAdd(&cnt[tid], hist[tid]);
}

__global__ void offsets_kernel(const int* __restrict__ cnt,
                               int* __restrict__ off, int* __restrict__ cnt2)
{
    if (threadIdx.x == 0) {
        int a = 0;
        for (int e = 0; e < N_EXPERTS; e++) { off[e] = a; a += cnt[e]; cnt2[e] = 0; }
        off[N_EXPERTS] = a;
    }
}

// ------- scatter via wave ballot-ranking -------
__global__ __launch_bounds__(64) void scatter_kernel(
    const int* __restrict__ route_pack, const int* __restrict__ off,
    int* __restrict__ cnt2, int* __restrict__ tok_id, int* __restrict__ inv)
{
    int lane = threadIdx.x;
    int t = blockIdx.x * 64 + lane;
    int p  = route_pack[t];
    int e0 = p & 0xff, e1 = (p >> 8) & 0xff;

    unsigned long long m0[N_EXPERTS], m1[N_EXPERTS];
    for (int e = 0; e < N_EXPERTS; e++) {
        m0[e] = __ballot(e0 == e);
        m1[e] = __ballot(e1 == e);
    }
    int mybase = 0;
    if (lane < N_EXPERTS)
        mybase = atomicAdd(&cnt2[lane], __popcll(m0[lane]) + __popcll(m1[lane]));

    unsigned long long lt = (1ull << lane) - 1ull;
    int b0 = __shfl(mybase, e0);
    int s0 = off[e0] + b0 + (int)__popcll(m0[e0] & lt);
    int b1 = __shfl(mybase, e1);
    int s1 = off[e1] + b1 + (int)__popcll(m0[e1]) + (int)__popcll(m1[e1] & lt);

    tok_id[s0] = t;
    tok_id[s1] = t;
    inv[2 * t]     = s0;
    inv[2 * t + 1] = s1;
}

// src: [E][R][C] fp32  ->  dst: [E][C][R] bf16   (64x64 tiles, 16B-coalesced)
template <int R, int C>
__global__ __launch_bounds__(256) void transpose_convert_kernel(
    const float* __restrict__ src, unsigned short* __restrict__ dst)
{
    __shared__ float tile[64 * 68];
    int e = blockIdx.z;
    const float* s = src + (size_t)e * R * C;
    unsigned short* d = dst + (size_t)e * R * C;
    int r0 = blockIdx.y * 64, c0 = blockIdx.x * 64;
    int t = threadIdx.x;
    {
        int r = t >> 4, c4 = (t & 15) * 4;
        for (int p = 0; p < 4; p++, r += 16)
            *(float4*)&tile[r * 68 + c4] = *(const float4*)&s[(size_t)(r0 + r) * C + c0 + c4];
    }
    __syncthreads();
    {
        int c = t >> 2, rblk = (t & 3) * 8;
        for (int q = 0; q < 2; q++) {
            int rr = q * 32 + rblk;
            ushort8 o;
            for (int j = 0; j < 8; j++) o[j] = f2bf(tile[(rr + j) * 68 + c]);
            *(ushort8*)&d[(size_t)(c0 + c) * R + r0 + rr] = o;
        }
    }
}

// ======== grouped GEMM: 256x256 tile, BK=64, double-buffer, safe schedule ========
// 512 thr = 8 waves (2M x 4N). Per-wave output 128x64 -> acc[8][4] (m201 geometry:
// 0.375 ds_read_b128 per MFMA vs 0.625 at BN=128 -> LDS-read floor drops 1.67x).
// LDS: 2 bufs x (A 256x64 + B 256x64) bf16 = 128 KB.
// Iter t: stage(tile t+1 -> buf cur^1) issued right after the barrier; compute buf cur
// (24 ds_read + 64 MFMA per wave hides the load latency); vmcnt(0); s_barrier.
// WAR safety: staging writes issue after the barrier that follows lgkmcnt-complete
// reads of that buffer's old tile -> cannot land early.
template<int KDIM, int NC, bool RELU, bool USE_TOK>
__global__ __launch_bounds__(512, 2) void moe_gemm_kernel(
    const unsigned short* __restrict__ Ag, const unsigned short* __restrict__ Bw,
    const float* __restrict__ bias, const int* __restrict__ tok_id,
    const int* __restrict__ off, unsigned short* __restrict__ Cout)
{
    constexpr int NT   = KDIM / 64;         // K-tiles (16 or 64)
    constexpr int NTN  = NC / 256;          // N-tiles
    constexpr int NWG  = MAX_MT * NTN;
    constexpr int ASH  = 256 * 64;          // A shorts per buffer (32 KB)
    constexpr int BUFS = 2 * ASH;           // shorts per buffer (A+B = 64 KB)
    __shared__ unsigned short smem[2 * BUFS];   // 128 KB

    // T1: bijective XCD swizzle (m204). Consecutive sz share bx -> A-panel L2 reuse.
    int wg = blockIdx.x;
    constexpr int qq8 = NWG / 8, rr8 = NWG % 8;
    int xcd = wg & 7, idx = wg >> 3;
    int sz = (xcd < rr8 ? xcd * (qq8 + 1) : rr8 * (qq8 + 1) + (xcd - rr8) * qq8) + idx;
    int bx = sz / NTN;
    int n0 = (sz % NTN) * 256;

    int e = -1, slot0 = 0, end = 0;
    {
        int acc = 0;
        for (int i = 0; i < N_EXPERTS; i++) {
            int s = off[i], en = off[i + 1];
            int nt = (en - s + 255) >> 8;
            if (e < 0 && bx < acc + nt) { e = i; slot0 = s + (bx - acc) * 256; end = en; }
            acc += nt;
        }
        if (e < 0) return;
    }

    int tid = threadIdx.x, wave = tid >> 6, lane = tid & 63;
    int wm = wave >> 2, wn = wave & 3;            // 2M x 4N
    int lr = lane >> 3, lc = lane & 7;
    int lcs = lc ^ lr;                            // T2 source-side chunk swizzle
    int row16 = lane & 15, qk = lane >> 4;
    int sx = row16 & 7;                           // T2 read-side chunk XOR

    f32x4 acc[8][4];
    const f32x4 zero = {0.f, 0.f, 0.f, 0.f};
#pragma unroll
    for (int i = 0; i < 8; i++)
#pragma unroll
        for (int j = 0; j < 4; j++) acc[i][j] = zero;

    // staging: wave w stages A rows [w*32, +32) and B rows [w*32, +32), 4 calls each
    const unsigned short* gA[4];
    const unsigned short* gB[4];
    int ldsA[4], ldsB[4];
#pragma unroll
    for (int c = 0; c < 4; c++) {
        int rowt = wave * 32 + c * 8 + lr;
        int slotc = min(slot0 + rowt, end - 1);
        int grow;
        if constexpr (USE_TOK) grow = tok_id[slotc]; else grow = slotc;
        gA[c] = Ag + (size_t)grow * KDIM + lcs * 8;
        gB[c] = Bw + ((size_t)e * NC + n0 + rowt) * KDIM + lcs * 8;
        ldsA[c] = (wave * 32 + c * 8) * 64;
        ldsB[c] = ASH + (wave * 32 + c * 8) * 64;
    }

    auto stage = [&](int b, int kt) {
        unsigned short* base = smem + b * BUFS;
#pragma unroll
        for (int c = 0; c < 4; c++) gl_lds16(gA[c] + kt * 64, base + ldsA[c]);
#pragma unroll
        for (int c = 0; c < 4; c++) gl_lds16(gB[c] + kt * 64, base + ldsB[c]);
    };

    // prologue: tile 0 -> buf 0, wait resident
    stage(0, 0);
    asm volatile("s_waitcnt vmcnt(0)" ::: "memory");
    __builtin_amdgcn_s_barrier();

    int cur = 0;
    for (int t = 0; t < NT; t++) {
        if (t + 1 < NT) stage(cur ^ 1, t + 1);   // issue early: full tile compute hides it
        const unsigned short* Ab = smem + cur * BUFS;
        const unsigned short* Bb = Ab + ASH;
        __builtin_amdgcn_s_setprio(1);
#pragma unroll
        for (int ks = 0; ks < 2; ks++) {
            bf16x8 af[8], bq[4];
#pragma unroll
            for (int i = 0; i < 8; i++) {
                int rr = wm * 128 + i * 16 + row16;
                af[i] = *(const bf16x8*)&Ab[rr * 64 + (((ks * 4 + qk) ^ sx) * 8)];
            }
#pragma unroll
            for (int j = 0; j < 4; j++) {
                int br = wn * 64 + j * 16 + row16;
                bq[j] = *(const bf16x8*)&Bb[br * 64 + (((ks * 4 + qk) ^ sx) * 8)];
            }
#pragma unroll
            for (int i = 0; i < 8; i++)
#pragma unroll
                for (int j = 0; j < 4; j++)
                    acc[i][j] = __builtin_amdgcn_mfma_f32_16x16x32_bf16(af[i], bq[j], acc[i][j], 0, 0, 0);
        }
        __builtin_amdgcn_s_setprio(0);
        asm volatile("s_waitcnt vmcnt(0)" ::: "memory");   // tile t+1 resident
        __builtin_amdgcn_s_barrier();
        cur ^= 1;
    }

    // epilogue: reuse LDS to stage 128-row output halves (128 x 264 shorts = 66 KB)
    unsigned short* stg = smem;
    int quad = lane >> 4, c16 = lane & 15;
    for (int p = 0; p < 2; p++) {
        if (p) __syncthreads();
        if (wm == p) {
#pragma unroll
            for (int j = 0; j < 4; j++) {
                int n = n0 + wn * 64 + j * 16 + c16;
                float bv = bias[e * NC + n];
#pragma unroll
                for (int i = 0; i < 8; i++)
#pragma unroll
                    for (int r = 0; r < 4; r++) {
                        float v = acc[i][j][r] + bv;
                        if (RELU) v = v > 0.f ? v : 0.f;
                        stg[(i * 16 + quad * 4 + r) * 264 + wn * 64 + j * 16 + c16] = f2bf(v);
                    }
            }
        }
        __syncthreads();
        int srow = tid >> 5, chunk = (tid & 31) * 8;
#pragma unroll
        for (int s8 = 0; s8 < 8; s8++) {
            int rr = srow + s8 * 16;
            int slot = slot0 + p * 128 + rr;
            if (slot < end)
                *(ushort8*)&Cout[(size_t)slot * NC + n0 + chunk] =
                    *(const ushort8*)&stg[rr * 264 + chunk];
        }
    }
}

// -------- combine: out[t] = w0*y[s0] + w1*y[s1] --------
__global__ __launch_bounds__(256) void combine_kernel(
    const unsigned short* __restrict__ y, const int* __restrict__ inv,
    const float* __restrict__ rw, float* __restrict__ out)
{
    int wave = threadIdx.x >> 6, lane = threadIdx.x & 63;
    int t = blockIdx.x * 4 + wave;
    int s0 = inv[2 * t], s1 = inv[2 * t + 1];
    float w0 = rw[2 * t], w1 = rw[2 * t + 1];
    const unsigned short* y0 = y + (size_t)s0 * D_MODEL;
    const unsigned short* y1 = y + (size_t)s1 * D_MODEL;
    float* orow = out + (size_t)t * D_MODEL;
    int c = lane * 16;
    for (int hh = 0; hh < 2; hh++) {
        ushort8 a = *(const ushort8*)&y0[c + hh * 8];
        ushort8 b = *(const ushort8*)&y1[c + hh * 8];
        float4 o0, o1;
        o0.x = w0 * bf2f(a[0]) + w1 * bf2f(b[0]);
        o0.y = w0 * bf2f(a[1]) + w1 * bf2f(b[1]);
        o0.z = w0 * bf2f(a[2]) + w1 * bf2f(b[2]);
        o0.w = w0 * bf2f(a[3]) + w1 * bf2f(b[3]);
        o1.x = w0 * bf2f(a[4]) + w1 * bf2f(b[4]);
        o1.y = w0 * bf2f(a[5]) + w1 * bf2f(b[5]);
        o1.z = w0 * bf2f(a[6]) + w1 * bf2f(b[6]);
        o1.w = w0 * bf2f(a[7]) + w1 * bf2f(b[7]);
        *(float4*)&orow[c + hh * 8]     = o0;
        *(float4*)&orow[c + hh * 8 + 4] = o1;
    }
}

// ---------------- launch ----------------
extern "C" void kernel_launch(void* const* d_in, const int* in_sizes, int n_in,
                              void* d_out, int out_size, void* d_ws, size_t ws_size,
                              hipStream_t stream)
{
    const float* x      = (const float*)d_in[0];
    const float* gate_w = (const float*)d_in[1];
    const float* w1     = (const float*)d_in[2];
    const float* b1     = (const float*)d_in[3];
    const float* w2     = (const float*)d_in[4];
    const float* b2     = (const float*)d_in[5];
    float* out = (float*)d_out;

    char* ws = (char*)d_ws;
    size_t o = 0;
    auto alloc = [&](size_t bytes) { void* p = ws + o; o += (bytes + 255) & ~(size_t)255; return p; };
    int*   cnt        = (int*)alloc(32);
    int*   cnt2       = (int*)alloc(32);
    int*   off        = (int*)alloc(64);
    int*   route_pack = (int*)alloc((size_t)T_TOKENS * 4);
    float* route_w    = (float*)alloc((size_t)T_TOKENS * 8);
    int*   tok_id     = (int*)alloc((size_t)N_SLOTS * 4);
    int*   inv        = (int*)alloc((size_t)T_TOKENS * 8);
    unsigned short* xb  = (unsigned short*)alloc((size_t)T_TOKENS * D_MODEL * 2);
    unsigned short* w1t = (unsigned short*)alloc((size_t)N_EXPERTS * D_MODEL * D_HIDDEN * 2);
    unsigned short* w2t = (unsigned short*)alloc((size_t)N_EXPERTS * D_MODEL * D_HIDDEN * 2);
    unsigned short* h   = (unsigned short*)alloc((size_t)N_SLOTS * D_HIDDEN * 2);
    // y aliases w1t (dead after gemm1)
    unsigned short* y   = w1t;

    hipMemsetAsync(cnt, 0, 32, stream);

    gate_kernel<<<T_TOKENS / 16, 256, 0, stream>>>(x, gate_w, xb, route_pack, route_w, cnt);
    offsets_kernel<<<1, 64, 0, stream>>>(cnt, off, cnt2);
    scatter_kernel<<<T_TOKENS / 64, 64, 0, stream>>>(route_pack, off, cnt2, tok_id, inv);
    transpose_convert_kernel<D_MODEL, D_HIDDEN>
        <<<dim3(D_HIDDEN / 64, D_MODEL / 64, N_EXPERTS), dim3(256), 0, stream>>>(w1, w1t);
    transpose_convert_kernel<D_HIDDEN, D_MODEL>
        <<<dim3(D_MODEL / 64, D_HIDDEN / 64, N_EXPERTS), dim3(256), 0, stream>>>(w2, w2t);
    moe_gemm_kernel<D_MODEL, D_HIDDEN, true, true>
        <<<dim3(MAX_MT * (D_HIDDEN / 256)), dim3(512), 0, stream>>>(xb, w1t, b1, tok_id, off, h);
    moe_gemm_kernel<D_HIDDEN, D_MODEL, false, false>
        <<<dim3(MAX_MT * (D_MODEL / 256)), dim3(512), 0, stream>>>(h, w2t, b2, tok_id, off, y);
    combine_kernel<<<T_TOKENS / 4, 256, 0, stream>>>(y, inv, route_w, out);
}